// Round 5
// baseline (145.588 us; speedup 1.0000x reference)
//
#include <hip/hip_runtime.h>
#include <hip/hip_bf16.h>

// Problem constants (fixed by the reference): B=16, V=8192, N=2048, H=128, C_OUT=7
#define B_GR   16
#define V_PTS  8192
#define N_RES  2048
#define H_DIM  128
#define C_OUT  7
#define SEGS   16            // pool kernel: residue segments per graph (128 residues each)

// argmin decomposition
#define NSPLIT 16                    // residue splits per graph
#define NL     (N_RES / NSPLIT)      // 128 residues per block
#define VPT    8                     // vertices per thread (8 independent FMA chains)
#define VBLK   (256 * VPT)           // 2048 vertices per block
#define VBLKS  (V_PTS / VBLK)        // 4 vertex-blocks per graph
// grid = B * VBLKS * NSPLIT = 1024 blocks -> 4 blocks/CU, 16 waves/CU.
// Ledger: r1: v_pk_*_f32 NOT double-rate on CDNA4. r2: occupancy 26->47% left
// dur flat -> issue-bound, not latency-bound. r3: atomics were free. r4:
// VPT=16 amortization bought only 2 µs; implied ~12 instr/pair at 70% busy.
// r5 theory: the residual is the s_waitcnt lgkmcnt right after the ds_reads
// (~120cy LDS latency exposed per unroll body) -> software-pipeline the
// broadcast sc[] read one iteration ahead so the wait lands after ~320 VALU.

// ---------------------------------------------------------------------------
// Kernel 1 (store path): partial nearest-residue argmin over a 128-residue
// slice, 8 vertices per thread. Bit-exact replication of the reference fp32
// sequence:
//   d = fadd( fma(-2, dot, vsq), csq ),  dot = fadd(fadd(x*cx, y*cy), z*cz)
// (fma(-2,dot,vsq) == RN(vsq - 2*dot) exactly since 2*dot is exact.)
// Per-split winner stored as (key u32 = monotone-flipped d bits, idx u8 =
// split-local argmin). Equal d within a split keeps first n (strict <);
// cross-split ties resolved in k_merge by ascending split order == smallest
// global index, matching np.argmin first-occurrence. d == -0.0 impossible
// (csq >= +0), so the flip transform's -0<+0 quirk never triggers.
// The (vb==0,ns==0) block of each graph also zeroes the graph's hit mask,
// replacing a separate hipMemsetAsync node (ordered before k_merge by the
// stream).
// ---------------------------------------------------------------------------
__global__ __launch_bounds__(256, 4) void k_argmin_st(const float* __restrict__ verts,
                                                      const float* __restrict__ coords,
                                                      unsigned int* __restrict__ pkey,
                                                      unsigned char* __restrict__ pidx,
                                                      float* __restrict__ msk) {
    __shared__ float4 sc[NL];                          // 2 KB
    const int b  = blockIdx.x / (VBLKS * NSPLIT);
    const int r  = blockIdx.x % (VBLKS * NSPLIT);
    const int vb = r / NSPLIT;
    const int ns = r % NSPLIT;

    if (r == 0) {                                      // one block per graph
#pragma unroll
        for (int i = threadIdx.x; i < N_RES; i += 256)
            msk[b * N_RES + i] = 0.0f;                 // replaces memset node
    }

    const float* cbase = coords + ((size_t)b * N_RES + ns * NL) * 3;
    if (threadIdx.x < NL) {
        const int i = threadIdx.x;
        float x = cbase[i * 3 + 0];
        float y = cbase[i * 3 + 1];
        float z = cbase[i * 3 + 2];
        float csq = __fadd_rn(__fadd_rn(__fmul_rn(x, x), __fmul_rn(y, y)), __fmul_rn(z, z));
        sc[i] = make_float4(x, y, z, csq);
    }
    __syncthreads();

    const int vbase = vb * VBLK + threadIdx.x;         // vertex index within graph
    const float* vp = verts + (size_t)b * V_PTS * 3;

    float vx[VPT], vy[VPT], vz[VPT], vsq[VPT], best[VPT];
    int bi[VPT];
#pragma unroll
    for (int k = 0; k < VPT; ++k) {
        const int v = vbase + k * 256;
        vx[k] = vp[v * 3 + 0];
        vy[k] = vp[v * 3 + 1];
        vz[k] = vp[v * 3 + 2];
        vsq[k] = __fadd_rn(__fadd_rn(__fmul_rn(vx[k], vx[k]), __fmul_rn(vy[k], vy[k])),
                           __fmul_rn(vz[k], vz[k]));
        best[k] = 3.402823466e+38f;
        bi[k] = 0;
    }

    // Software-pipelined broadcast read: prefetch sc[n+2]/sc[n+3] BEFORE the
    // 2x16x10 VALU body that consumes sc[n]/sc[n+1], so the compiler's
    // s_waitcnt lgkmcnt lands ~320 instructions after the ds_read issues
    // (LDS latency ~120cy fully hidden) instead of immediately after.
    float4 ca = sc[0];
    float4 cb = sc[1];
#pragma unroll 1
    for (int n = 0; n < NL; n += 2) {
        const float4 pa = sc[(n + 2) & (NL - 1)];      // harmless wrap at tail
        const float4 pb = sc[(n + 3) & (NL - 1)];
#pragma unroll
        for (int k = 0; k < VPT; ++k) {
            float dot = __fadd_rn(__fadd_rn(__fmul_rn(vx[k], ca.x), __fmul_rn(vy[k], ca.y)),
                                  __fmul_rn(vz[k], ca.z));
            float d = __fadd_rn(fmaf(-2.0f, dot, vsq[k]), ca.w);
            bool m = d < best[k];                      // strict <: first index wins
            best[k] = m ? d : best[k];
            bi[k]   = m ? n : bi[k];
        }
#pragma unroll
        for (int k = 0; k < VPT; ++k) {
            float dot = __fadd_rn(__fadd_rn(__fmul_rn(vx[k], cb.x), __fmul_rn(vy[k], cb.y)),
                                  __fmul_rn(vz[k], cb.z));
            float d = __fadd_rn(fmaf(-2.0f, dot, vsq[k]), cb.w);
            bool m = d < best[k];
            best[k] = m ? d : best[k];
            bi[k]   = m ? n + 1 : bi[k];
        }
        ca = pa; cb = pb;
    }

    unsigned int*  kb = pkey + ((size_t)(b * NSPLIT + ns)) * V_PTS + vbase;
    unsigned char* ib = pidx + ((size_t)(b * NSPLIT + ns)) * V_PTS + vbase;
#pragma unroll
    for (int k = 0; k < VPT; ++k) {
        unsigned int bits = __float_as_uint(best[k]);
        unsigned int key  = bits ^ (unsigned int)(((int)bits >> 31) | 0x80000000);
        kb[k * 256] = key;                             // plain coalesced stores
        ib[k * 256] = (unsigned char)bi[k];            // NL=128 fits u8
    }
}

// ---------------------------------------------------------------------------
// Kernel 1b (merge): per-vertex min over the 16 per-split key candidates
// (ascending strict < keeps the earliest split == smallest global index on
// ties), fetch that split's local idx byte, scatter 1.0f into the global hit
// mask (race-benign). 512 blocks x 256 threads; 16 coalesced u32 loads.
// ---------------------------------------------------------------------------
__global__ __launch_bounds__(256) void k_merge(const unsigned int* __restrict__ pkey,
                                               const unsigned char* __restrict__ pidx,
                                               float* __restrict__ msk) {
    const int gv = blockIdx.x * 256 + threadIdx.x;     // 0 .. B*V-1
    const int b  = gv >> 13;                           // / V_PTS
    const int v  = gv & (V_PTS - 1);

    const unsigned int* p = pkey + (size_t)b * NSPLIT * V_PTS + v;
    unsigned int ck[NSPLIT];
#pragma unroll
    for (int s = 0; s < NSPLIT; ++s)                   // batch all loads first
        ck[s] = p[(size_t)s * V_PTS];
    unsigned int bk = ck[0];
    int bs = 0;
#pragma unroll
    for (int s = 1; s < NSPLIT; ++s) {
        bool m = ck[s] < bk;                           // strict <: earliest split wins
        bk = m ? ck[s] : bk;
        bs = m ? s : bs;
    }
    const unsigned int li =
        pidx[((size_t)b * NSPLIT + bs) * V_PTS + v];
    msk[b * N_RES + bs * NL + li] = 1.0f;              // global residue index
}

// ---------------------------------------------------------------------------
// Kernel 2 (store path): masked-sum a 128-residue slice of feats with float4
// loads; mask slice staged from the tiny global msk array (512 B).
// Grid: B*SEGS = 256 blocks, 256 threads: lane-quad q=tid&31 covers H=128 as
// float4; slice s=tid>>5 gives 8-way n-parallelism, LDS-reduced at the end.
// ---------------------------------------------------------------------------
__global__ __launch_bounds__(256) void k_pool_m(const float* __restrict__ msk,
                                                const float* __restrict__ feats,
                                                float* __restrict__ partial) {
    __shared__ float sm[NL];                            // 512 B mask slice
    __shared__ float4 red[8][32];
    const int b   = blockIdx.x >> 4;
    const int seg = blockIdx.x & (SEGS - 1);
    const int n0  = seg * (N_RES / SEGS);               // N_RES/SEGS == NL == 128

    if (threadIdx.x < NL) sm[threadIdx.x] = msk[b * N_RES + n0 + threadIdx.x];
    __syncthreads();

    const int q = threadIdx.x & 31;                     // float4 column (h = 4q..4q+3)
    const int s = threadIdx.x >> 5;                     // n-slice 0..7
    const float4* fb4 = (const float4*)(feats + ((size_t)b * N_RES + n0) * H_DIM);

    float4 acc = make_float4(0.f, 0.f, 0.f, 0.f);
#pragma unroll
    for (int n = 0; n < N_RES / SEGS / 8; ++n) {
        const int nn = s + n * 8;
        const float m = sm[nn];
        const float4 f = fb4[(size_t)nn * 32 + q];
        acc.x = fmaf(f.x, m, acc.x);
        acc.y = fmaf(f.y, m, acc.y);
        acc.z = fmaf(f.z, m, acc.z);
        acc.w = fmaf(f.w, m, acc.w);
    }
    red[s][q] = acc;
    __syncthreads();

    if (s == 0) {
        float4 t = acc;
#pragma unroll
        for (int i = 1; i < 8; ++i) {
            t.x += red[i][q].x; t.y += red[i][q].y;
            t.z += red[i][q].z; t.w += red[i][q].w;
        }
        ((float4*)partial)[((size_t)b * SEGS + seg) * 32 + q] = t;
    }
}

// ---------------------------------------------------------------------------
// Fallback path (small workspace): round-0 atomicMin kernels, verbatim.
// ---------------------------------------------------------------------------
__global__ __launch_bounds__(256, 4) void k_argmin_at(const float* __restrict__ verts,
                                                      const float* __restrict__ coords,
                                                      unsigned long long* __restrict__ mi64) {
    __shared__ float4 sc[NL];
    const int b  = blockIdx.x / (VBLKS * NSPLIT);
    const int r  = blockIdx.x % (VBLKS * NSPLIT);
    const int vb = r / NSPLIT;
    const int ns = r % NSPLIT;

    const float* cbase = coords + ((size_t)b * N_RES + ns * NL) * 3;
    if (threadIdx.x < NL) {
        const int i = threadIdx.x;
        float x = cbase[i * 3 + 0];
        float y = cbase[i * 3 + 1];
        float z = cbase[i * 3 + 2];
        float csq = __fadd_rn(__fadd_rn(__fmul_rn(x, x), __fmul_rn(y, y)), __fmul_rn(z, z));
        sc[i] = make_float4(x, y, z, csq);
    }
    __syncthreads();

    const int vbase = vb * VBLK + threadIdx.x;
    const float* vp = verts + (size_t)b * V_PTS * 3;

    float vx[VPT], vy[VPT], vz[VPT], vsq[VPT], best[VPT];
    int bi[VPT];
#pragma unroll
    for (int k = 0; k < VPT; ++k) {
        const int v = vbase + k * 256;
        vx[k] = vp[v * 3 + 0];
        vy[k] = vp[v * 3 + 1];
        vz[k] = vp[v * 3 + 2];
        vsq[k] = __fadd_rn(__fadd_rn(__fmul_rn(vx[k], vx[k]), __fmul_rn(vy[k], vy[k])),
                           __fmul_rn(vz[k], vz[k]));
        best[k] = 3.402823466e+38f;
        bi[k] = 0;
    }
#pragma unroll 2
    for (int n = 0; n < NL; ++n) {
        const float4 c = sc[n];
#pragma unroll
        for (int k = 0; k < VPT; ++k) {
            float dot = __fadd_rn(__fadd_rn(__fmul_rn(vx[k], c.x), __fmul_rn(vy[k], c.y)),
                                  __fmul_rn(vz[k], c.z));
            float d = __fadd_rn(fmaf(-2.0f, dot, vsq[k]), c.w);
            bool m = d < best[k];
            best[k] = m ? d : best[k];
            bi[k]   = m ? n : bi[k];
        }
    }
#pragma unroll
    for (int k = 0; k < VPT; ++k) {
        unsigned int bits = __float_as_uint(best[k]);
        unsigned int key  = bits ^ (unsigned int)(((int)bits >> 31) | 0x80000000);
        unsigned long long packed =
            ((unsigned long long)key << 32) | (unsigned int)(ns * NL + bi[k]);
        atomicMin(&mi64[(size_t)b * V_PTS + vbase + k * 256], packed);
    }
}

__global__ __launch_bounds__(256) void k_pool_at(const unsigned long long* __restrict__ mi64,
                                                 const float* __restrict__ feats,
                                                 float* __restrict__ partial) {
    __shared__ float msk[N_RES];
    __shared__ float4 red[8][32];
    const int b   = blockIdx.x >> 4;
    const int seg = blockIdx.x & (SEGS - 1);

    for (int i = threadIdx.x; i < N_RES; i += 256) msk[i] = 0.0f;
    __syncthreads();
    const unsigned long long* mb = mi64 + (size_t)b * V_PTS;
    for (int v = threadIdx.x; v < V_PTS; v += 256)
        msk[(unsigned int)mb[v]] = 1.0f;
    __syncthreads();

    const int q = threadIdx.x & 31;
    const int s = threadIdx.x >> 5;
    const int n0 = seg * (N_RES / SEGS);
    const float4* fb4 = (const float4*)(feats + ((size_t)b * N_RES + n0) * H_DIM);

    float4 acc = make_float4(0.f, 0.f, 0.f, 0.f);
#pragma unroll
    for (int n = 0; n < N_RES / SEGS / 8; ++n) {
        const int nn = s + n * 8;
        const float m = msk[n0 + nn];
        const float4 f = fb4[(size_t)nn * 32 + q];
        acc.x = fmaf(f.x, m, acc.x);
        acc.y = fmaf(f.y, m, acc.y);
        acc.z = fmaf(f.z, m, acc.z);
        acc.w = fmaf(f.w, m, acc.w);
    }
    red[s][q] = acc;
    __syncthreads();
    if (s == 0) {
        float4 t = acc;
#pragma unroll
        for (int i = 1; i < 8; ++i) {
            t.x += red[i][q].x; t.y += red[i][q].y;
            t.z += red[i][q].z; t.w += red[i][q].w;
        }
        ((float4*)partial)[((size_t)b * SEGS + seg) * 32 + q] = t;
    }
}

// ---------------------------------------------------------------------------
// Kernel 3: per-graph block — reduce 16 seg partials -> pooled[H], then
// relu(pooled@W1+b1)@W2+b2 -> out[b][7]. 16 blocks x 128 threads.
// (r1 lesson: last-block-done fusion costs ~19 µs via device-scope
// threadfence on non-coherent XCD L2s. Separate tiny launch is cheaper.)
// ---------------------------------------------------------------------------
__global__ __launch_bounds__(128) void k_mlp(const float* __restrict__ partial,
                                             const float* __restrict__ W1,
                                             const float* __restrict__ b1,
                                             const float* __restrict__ W2,
                                             const float* __restrict__ b2,
                                             float* __restrict__ out) {
    __shared__ float pooled[H_DIM];
    __shared__ float h1[H_DIM];
    const int b = blockIdx.x;
    const int j = threadIdx.x;

    float s = 0.0f;
#pragma unroll
    for (int g = 0; g < SEGS; ++g)
        s += partial[((size_t)b * SEGS + g) * H_DIM + j];
    pooled[j] = s;
    __syncthreads();

    float acc = b1[j];
#pragma unroll 8
    for (int hh = 0; hh < H_DIM; ++hh)
        acc = fmaf(pooled[hh], W1[hh * H_DIM + j], acc);
    h1[j] = fmaxf(acc, 0.0f);
    __syncthreads();

    if (j < C_OUT) {
        float o = b2[j];
#pragma unroll 8
        for (int hh = 0; hh < H_DIM; ++hh)
            o = fmaf(h1[hh], W2[hh * C_OUT + j], o);
        out[(size_t)b * C_OUT + j] = o;
    }
}

extern "C" void kernel_launch(void* const* d_in, const int* in_sizes, int n_in,
                              void* d_out, int out_size, void* d_ws, size_t ws_size,
                              hipStream_t stream) {
    const float* verts  = (const float*)d_in[0];   // [B,V,3]
    const float* coords = (const float*)d_in[1];   // [B,N,3]
    const float* feats  = (const float*)d_in[2];   // [B,N,H]
    const float* W1     = (const float*)d_in[3];   // [H,H]
    const float* b1     = (const float*)d_in[4];   // [H]
    const float* W2     = (const float*)d_in[5];   // [H,C_OUT]
    const float* b2     = (const float*)d_in[6];   // [C_OUT]
    float* out = (float*)d_out;                    // [B,C_OUT]

    const size_t key_bytes = (size_t)B_GR * NSPLIT * V_PTS * 4;    // 8 MB
    const size_t idx_bytes = (size_t)B_GR * NSPLIT * V_PTS;        // 2 MB
    const size_t msk_bytes = (size_t)B_GR * N_RES * 4;             // 128 KB
    const size_t pp_bytes  = (size_t)B_GR * SEGS * H_DIM * 4;      // 128 KB

    if (ws_size >= key_bytes + idx_bytes + msk_bytes + pp_bytes) {
        // ---- store + merge path (no device atomics, no memset node) ----
        unsigned int*  pkey = (unsigned int*)d_ws;
        unsigned char* pidx = (unsigned char*)d_ws + key_bytes;
        float* msk     = (float*)((char*)d_ws + key_bytes + idx_bytes);
        float* partial = (float*)((char*)d_ws + key_bytes + idx_bytes + msk_bytes);

        k_argmin_st<<<B_GR * VBLKS * NSPLIT, 256, 0, stream>>>(verts, coords, pkey, pidx, msk);
        k_merge    <<<B_GR * V_PTS / 256,    256, 0, stream>>>(pkey, pidx, msk);
        k_pool_m   <<<B_GR * SEGS,           256, 0, stream>>>(msk, feats, partial);
        k_mlp      <<<B_GR,                  128, 0, stream>>>(partial, W1, b1, W2, b2, out);
    } else {
        // ---- fallback: round-0 atomicMin path ----
        unsigned long long* mi64 = (unsigned long long*)d_ws;              // 1 MB
        float* partial = (float*)((char*)d_ws + (size_t)B_GR * V_PTS * 8); // 128 KB

        hipMemsetAsync(mi64, 0xFF, (size_t)B_GR * V_PTS * 8, stream);
        k_argmin_at<<<B_GR * VBLKS * NSPLIT, 256, 0, stream>>>(verts, coords, mi64);
        k_pool_at  <<<B_GR * SEGS,           256, 0, stream>>>(mi64, feats, partial);
        k_mlp      <<<B_GR,                  128, 0, stream>>>(partial, W1, b1, W2, b2, out);
    }
}